// Round 7
// baseline (648.189 us; speedup 1.0000x reference)
//
#include <hip/hip_runtime.h>
#include <hip/hip_bf16.h>

#define BATCH   65536
#define NCHAN   12
#define LRAW    63
#define CHF     168
#define FLEN    7
#define FGH     35
#define EN1     16
#define EN2     32
#define KWID    6
#define LC1     18
#define LC2     5

#define SH1     64      // bn1 stat shards
#define SH2     32      // bn2 stat shards

// ---- workspace layout (float units) ----
static const size_t WS_STATS1 = 0;                                 // 2048  (64 shards x [sum16|sq16])
static const size_t WS_STATS2 = 2048;                              // 2048  (32 shards x [sum32|sq32])
static const size_t WS_W1T    = 4096;                              // 1152
static const size_t WS_W2T    = WS_W1T + 1152;                     // 3072
static const size_t WS_FILT   = WS_W2T + 3072;                     // BATCH*8
static const size_t WS_C1     = WS_FILT + (size_t)BATCH * 8;       // bf16 [18][B][16] = 9437184 floats
static const size_t WS_C2     = WS_C1 + (size_t)18 * BATCH * 16 / 2; // bf16 [160][B] = 5242880 floats
// total ~15.2M floats = 61 MB

// fast tanh: 1 - 2/(e^2x + 1) via v_exp_f32 + v_rcp_f32 (abs err ~1e-5, threshold 0.074)
__device__ __forceinline__ float ftanh(float x) {
    float e = __expf(2.0f * x);
    return fmaf(-2.0f, __builtin_amdgcn_rcpf(e + 1.0f), 1.0f);
}
// f32 -> bf16 bits, round-to-nearest-even
__device__ __forceinline__ unsigned int bfr(float x) {
    unsigned int u = __float_as_uint(x);
    return (u + 0x7fffu + ((u >> 16) & 1u)) >> 16;
}
__device__ __forceinline__ float bf2f(unsigned int us) {
    return __uint_as_float(us << 16);
}

// K0: zero shard stats, transpose conv weights to oc-contiguous layout
__global__ void k_init(const float* __restrict__ ew1, const float* __restrict__ ew2,
                       float* __restrict__ w1t, float* __restrict__ w2t,
                       float* __restrict__ stats) {
    int t = threadIdx.x;
    for (int i = t; i < 4096; i += 256) stats[i] = 0.f;
    for (int i = t; i < EN1 * NCHAN * KWID; i += 256) {
        int oc = i / (NCHAN * KWID); int r = i % (NCHAN * KWID);
        w1t[r * EN1 + oc] = ew1[i];
    }
    for (int i = t; i < EN2 * EN1 * KWID; i += 256) {
        int oc = i / (EN1 * KWID); int r = i % (EN1 * KWID);
        w2t[r * EN2 + oc] = ew2[i];
    }
}

// K1: filter generator MLP, one sample per lane
__global__ __launch_bounds__(256) void k_fg(
        const float* __restrict__ eegf,
        const float* __restrict__ w1, const float* __restrict__ b1,
        const float* __restrict__ w2, const float* __restrict__ b2,
        float* __restrict__ filt) {
    int b = blockIdx.x * 256 + threadIdx.x;
    const float* xr = eegf + (size_t)b * CHF;
    float acc[FGH];
#pragma unroll
    for (int j = 0; j < FGH; j++) acc[j] = b1[j];
#pragma unroll 1
    for (int t0 = 0; t0 < CHF; t0 += 56) {
        float x[56];
#pragma unroll
        for (int q = 0; q < 14; q++) {
            float4 v = *reinterpret_cast<const float4*>(xr + t0 + 4 * q);
            x[4*q] = v.x; x[4*q+1] = v.y; x[4*q+2] = v.z; x[4*q+3] = v.w;
        }
#pragma unroll 5
        for (int j = 0; j < FGH; j++) {
            const float* wr = w1 + (size_t)j * CHF + t0;     // uniform -> s_load
            float s0 = 0.f, s1 = 0.f, s2 = 0.f, s3 = 0.f;
#pragma unroll
            for (int q = 0; q < 14; q++) {
                s0 = fmaf(x[4*q],   wr[4*q],   s0);
                s1 = fmaf(x[4*q+1], wr[4*q+1], s1);
                s2 = fmaf(x[4*q+2], wr[4*q+2], s2);
                s3 = fmaf(x[4*q+3], wr[4*q+3], s3);
            }
            acc[j] += (s0 + s1) + (s2 + s3);
        }
    }
    float fa[FLEN];
#pragma unroll
    for (int k = 0; k < FLEN; k++) fa[k] = b2[k];
#pragma unroll 1
    for (int j = 0; j < FGH; j++) {
        float h = ftanh(acc[j]);
#pragma unroll
        for (int k = 0; k < FLEN; k++) fa[k] = fmaf(h, w2[k * FGH + j], fa[k]);
    }
    float4 o0, o1;
    o0.x = ftanh(fa[0]); o0.y = ftanh(fa[1]); o0.z = ftanh(fa[2]); o0.w = ftanh(fa[3]);
    o1.x = ftanh(fa[4]); o1.y = ftanh(fa[5]); o1.z = ftanh(fa[6]); o1.w = 0.f;
    float4* fo = reinterpret_cast<float4*>(filt + (size_t)b * 8);
    fo[0] = o0; fo[1] = o1;
}

// K2: 2 tiles x 16 samples per block; LDS-staged raw, reg-prefetch of tile1,
// on-the-fly adaptive filter + conv1; bf16 plane-major c1 stores; butterfly stats.
__global__ __launch_bounds__(320) void k_conv1(
        const float* __restrict__ raw, const float* __restrict__ encb1,
        const float* __restrict__ filtbuf, const float* __restrict__ w1t,
        unsigned short* __restrict__ c1, float* __restrict__ stats1) {
    __shared__ float4 rawt4[3024];          // 16 samples x 756 floats
    __shared__ float filts[2][16][8];
    __shared__ float part[5][32];
    float* rawt = (float*)rawt4;
    const int tid = threadIdx.x;
    const int s0b = blockIdx.x * 32;        // 32 samples = 2 tiles
    const float4* src4 = reinterpret_cast<const float4*>(raw + (size_t)s0b * 756);
    // stage tile 0
#pragma unroll
    for (int k = 0; k < 10; k++) {
        int idx = tid + k * 320;
        if (idx < 3024) rawt4[idx] = src4[idx];
    }
    if (tid < 256) {                        // filters for both tiles (slot7 = 0 pad)
        int tl = tid >> 7, r = tid & 127, s = r >> 3, k = r & 7;
        filts[tl][s][k] = filtbuf[(size_t)(s0b + tl * 16 + s) * 8 + k];
    }
    __syncthreads();
    // prefetch tile 1 into registers (latency hides under tile-0 compute)
    float4 rr[10];
#pragma unroll
    for (int k = 0; k < 10; k++) {
        int idx = tid + k * 320;
        if (idx < 3024) rr[k] = src4[3024 + idx];
    }
    const int s = tid & 15;
    const int pg = tid >> 4;                // 0..19, active < 18
    const int wv = tid >> 6;
#pragma unroll 1
    for (int tl = 0; tl < 2; tl++) {
        float acc[EN1];
        if (pg < 18) {
#pragma unroll
            for (int o = 0; o < EN1; o++) acc[o] = encb1[o];
            const float f0 = filts[tl][s][0], f1 = filts[tl][s][1], f2 = filts[tl][s][2],
                        f3 = filts[tl][s][3], f4 = filts[tl][s][4], f5 = filts[tl][s][5],
                        f6 = filts[tl][s][6];
            const float* rbase = rawt + s * 756 + 3 * pg;
#pragma unroll 1
            for (int c = 0; c < NCHAN; c++) {
                const float* rp = rbase + c * 63;
                float rv[12];
#pragma unroll
                for (int j = 0; j < 12; j++) rv[j] = rp[j];
                float e[KWID];
#pragma unroll
                for (int j = 0; j < KWID; j++) {
                    float v = f0 * rv[j];
                    v = fmaf(f1, rv[j+1], v);
                    v = fmaf(f2, rv[j+2], v);
                    v = fmaf(f3, rv[j+3], v);
                    v = fmaf(f4, rv[j+4], v);
                    v = fmaf(f5, rv[j+5], v);
                    v = fmaf(f6, rv[j+6], v);
                    e[j] = v;
                }
                const float* wp = w1t + c * (KWID * EN1);    // uniform -> s_load
#pragma unroll
                for (int j = 0; j < KWID; j++)
#pragma unroll
                    for (int o = 0; o < EN1; o++)
                        acc[o] = fmaf(e[j], wp[j * EN1 + o], acc[o]);
            }
            // bf16 plane-major store: c1[pg][s0b+tl*16+s][0..15] — 2x16B coalesced
            unsigned int w[8];
#pragma unroll
            for (int o = 0; o < 8; o++)
                w[o] = bfr(acc[2*o]) | (bfr(acc[2*o+1]) << 16);
            size_t base = ((size_t)pg * BATCH + (size_t)(s0b + tl*16 + s)) * 16;
            uint4* dst = reinterpret_cast<uint4*>(c1 + base);
            dst[0] = make_uint4(w[0], w[1], w[2], w[3]);
            dst[1] = make_uint4(w[4], w[5], w[6], w[7]);
        } else {
#pragma unroll
            for (int o = 0; o < EN1; o++) acc[o] = 0.f;
        }
        // wave butterfly: per-oc sum & sumsq over all 64 lanes
        float sq[EN1];
#pragma unroll
        for (int o = 0; o < EN1; o++) sq[o] = acc[o] * acc[o];
#pragma unroll
        for (int m = 1; m < 64; m <<= 1) {
#pragma unroll
            for (int o = 0; o < EN1; o++) {
                acc[o] += __shfl_xor(acc[o], m);
                sq[o]  += __shfl_xor(sq[o], m);
            }
        }
        if ((tid & 63) == 0) {
#pragma unroll
            for (int o = 0; o < EN1; o++) {
                part[wv][o]      = acc[o];
                part[wv][16 + o] = sq[o];
            }
        }
        __syncthreads();
        if (tid < 32) {
            float v = part[0][tid] + part[1][tid] + part[2][tid] + part[3][tid] + part[4][tid];
            atomicAdd(stats1 + (blockIdx.x & (SH1 - 1)) * 32 + tid, v);
        }
        if (tl == 0) {                      // overwrite LDS with prefetched tile 1
#pragma unroll
            for (int k = 0; k < 10; k++) {
                int idx = tid + k * 320;
                if (idx < 3024) rawt4[idx] = rr[k];
            }
            __syncthreads();
        }
    }
}

// K4: inline bnfin1, bf16 plane staging + BN1 + ftanh, conv2, direct bf16 c2 stores,
// butterfly BN2 stats (sharded)
__global__ __launch_bounds__(256) void k_conv2(
        const float* __restrict__ encb2,
        const float* __restrict__ bn1g, const float* __restrict__ bn1b,
        const float* __restrict__ stats1, const float* __restrict__ w2t,
        const unsigned short* __restrict__ c1, unsigned short* __restrict__ c2,
        float* __restrict__ stats2) {
    __shared__ float e1s[32 * 289];         // [s*289 + c*18 + t]
    __shared__ float bn1c[32];
    __shared__ float part[4][64];
    const int tid = threadIdx.x;
    const int s0b = blockIdx.x * 32;
    if (tid < 16) {                         // redundant per-block BN1 finalize
        float sm = 0.f, sqr = 0.f;
#pragma unroll 8
        for (int i = 0; i < SH1; i++) {
            sm  += stats1[i * 32 + tid];
            sqr += stats1[i * 32 + 16 + tid];
        }
        const float invn = 1.0f / ((float)BATCH * (float)LC1);
        float mean = sm * invn;
        float var  = sqr * invn - mean * mean;
        float a = bn1g[tid] * rsqrtf(var + 1e-5f);
        bn1c[tid] = a;
        bn1c[16 + tid] = bn1b[tid] - mean * a;
    }
    __syncthreads();
    // stage: 18 planes x 64 uint4 (each = 8 bf16 oc values), fully coalesced
    const uint4* c1u = reinterpret_cast<const uint4*>(c1);
#pragma unroll
    for (int k = 0; k < 5; k++) {
        int idx = tid + k * 256;
        if (idx < 1152) {
            int p = idx >> 6, rem = idx & 63, ss = rem >> 1, half = rem & 1;
            uint4 v = c1u[((size_t)p * BATCH + (s0b + ss)) * 2 + half];
            unsigned int ww[4] = {v.x, v.y, v.z, v.w};
            float* eb = e1s + ss * 289 + p;
#pragma unroll
            for (int u = 0; u < 4; u++) {
                int oc0 = half * 8 + 2 * u;
                float f0 = bf2f(ww[u] & 0xffffu);
                float f1 = __uint_as_float(ww[u] & 0xffff0000u);
                eb[oc0 * 18]       = ftanh(fmaf(f0, bn1c[oc0],     bn1c[16 + oc0]));
                eb[(oc0 + 1) * 18] = ftanh(fmaf(f1, bn1c[oc0 + 1], bn1c[16 + oc0 + 1]));
            }
        }
    }
    __syncthreads();
    const int s = tid & 31, p = tid >> 5;   // active p < 5
    const bool act = (p < 5);
    float acc[EN2];
    if (act) {
#pragma unroll
        for (int o = 0; o < EN2; o++) acc[o] = encb2[o];
        const float* eS = e1s + s * 289;
#pragma unroll 1
        for (int c = 0; c < EN1; c++) {
#pragma unroll
            for (int j = 0; j < KWID; j++) {
                float ev = eS[c * 18 + 3 * p + j];
                const float* wp = w2t + (c * KWID + j) * EN2;   // uniform -> s_load
#pragma unroll
                for (int o = 0; o < EN2; o++) acc[o] = fmaf(ev, wp[o], acc[o]);
            }
        }
        // direct bf16 feature-major stores: c2[oc*5+p][s0b+s]
#pragma unroll
        for (int o = 0; o < EN2; o++)
            c2[(size_t)(o * 5 + p) * BATCH + (s0b + s)] = (unsigned short)bfr(acc[o]);
    } else {
#pragma unroll
        for (int o = 0; o < EN2; o++) acc[o] = 0.f;
    }
    // wave butterfly stats
    float sq[EN2];
#pragma unroll
    for (int o = 0; o < EN2; o++) sq[o] = acc[o] * acc[o];
#pragma unroll
    for (int m = 1; m < 64; m <<= 1) {
#pragma unroll
        for (int o = 0; o < EN2; o++) {
            acc[o] += __shfl_xor(acc[o], m);
            sq[o]  += __shfl_xor(sq[o], m);
        }
    }
    const int lane = tid & 63, wv = tid >> 6;
    if (lane == 0) {
#pragma unroll
        for (int o = 0; o < EN2; o++) part[wv][o] = acc[o];
    }
    if (lane == 1) {
#pragma unroll
        for (int o = 0; o < EN2; o++) part[wv][32 + o] = sq[o];
    }
    __syncthreads();
    if (tid < 64) {
        float v = part[0][tid] + part[1][tid] + part[2][tid] + part[3][tid];
        atomicAdd(stats2 + (blockIdx.x & (SH2 - 1)) * 64 + tid, v);
    }
}

// K6: inline bnfin2; 4 lanes/sample; BN2+ftanh streamed into mu/logvar dots,
// reparameterize, decoder, outputs
__global__ __launch_bounds__(256) void k_head(
        const float* __restrict__ eps,
        const float* __restrict__ muw, const float* __restrict__ mub,
        const float* __restrict__ lvw, const float* __restrict__ lvb,
        const float* __restrict__ dw1, const float* __restrict__ db1,
        const float* __restrict__ dw2, const float* __restrict__ db2,
        const unsigned short* __restrict__ c2, const float* __restrict__ stats2,
        const float* __restrict__ bn2g, const float* __restrict__ bn2b,
        float* __restrict__ out) {
    __shared__ float bn2c[64];
    const int tid = threadIdx.x;
    if (tid < 32) {                         // redundant per-block BN2 finalize
        float sm = 0.f, sqr = 0.f;
#pragma unroll 8
        for (int i = 0; i < SH2; i++) {
            sm  += stats2[i * 64 + tid];
            sqr += stats2[i * 64 + 32 + tid];
        }
        const float invn = 1.0f / ((float)BATCH * (float)LC2);
        float mean = sm * invn;
        float var  = sqr * invn - mean * mean;
        float a = bn2g[tid] * rsqrtf(var + 1e-5f);
        bn2c[tid] = a;
        bn2c[32 + tid] = bn2b[tid] - mean * a;
    }
    __syncthreads();
    int gid = blockIdx.x * 256 + tid;
    int b = gid >> 2, q = gid & 3;
    const unsigned short* cp = c2 + (size_t)q * 40 * BATCH + b;
    float m0 = 0.f, m1 = 0.f, l0 = 0.f, l1 = 0.f;
#pragma unroll
    for (int t = 0; t < 40; t++) {
        int idx = q * 40 + t;               // feature index (runtime q, const t)
        int ch = q * 8 + (t / 5);           // compile-folded t/5
        float x = bf2f((unsigned int)cp[(size_t)t * BATCH]);
        float h = ftanh(fmaf(x, bn2c[ch], bn2c[32 + ch]));
        m0 = fmaf(h, muw[idx],       m0);
        m1 = fmaf(h, muw[160 + idx], m1);
        l0 = fmaf(h, lvw[idx],       l0);
        l1 = fmaf(h, lvw[160 + idx], l1);
    }
#pragma unroll
    for (int m = 1; m <= 2; m <<= 1) {
        m0 += __shfl_xor(m0, m); m1 += __shfl_xor(m1, m);
        l0 += __shfl_xor(l0, m); l1 += __shfl_xor(l1, m);
    }
    m0 += mub[0]; m1 += mub[1]; l0 += lvb[0]; l1 += lvb[1];
    float2 ev = *reinterpret_cast<const float2*>(eps + (size_t)b * 2);
    float z0 = fmaf(ev.x, __expf(0.5f * l0), m0);
    float z1 = fmaf(ev.y, __expf(0.5f * l1), m1);
    float d[10];
#pragma unroll
    for (int j = 0; j < 10; j++)
        d[j] = ftanh(fmaf(z1, dw1[j * 2 + 1], fmaf(z0, dw1[j * 2], db1[j])));
    float* orow = out + (size_t)b * 50;
    int nkk = (q == 3) ? 7 : 6;             // 25 float2 chunks split 6/6/6/7
#pragma unroll 1
    for (int kk = 0; kk < nkk; kk++) {
        int o = (q * 6 + kk) * 2;
        float s0 = db2[o], s1 = db2[o + 1];
#pragma unroll
        for (int j = 0; j < 10; j++) {
            s0 = fmaf(d[j], dw2[o * 10 + j],       s0);
            s1 = fmaf(d[j], dw2[(o + 1) * 10 + j], s1);
        }
        float2 w; w.x = ftanh(s0); w.y = ftanh(s1);
        *reinterpret_cast<float2*>(orow + o) = w;
    }
    if (q == 0)
        *reinterpret_cast<float2*>(out + (size_t)BATCH * 50 + (size_t)b * 2) = make_float2(m0, m1);
    if (q == 1)
        *reinterpret_cast<float2*>(out + (size_t)BATCH * 52 + (size_t)b * 2) = make_float2(l0, l1);
}

extern "C" void kernel_launch(void* const* d_in, const int* in_sizes, int n_in,
                              void* d_out, int out_size, void* d_ws, size_t ws_size,
                              hipStream_t stream) {
    (void)in_sizes; (void)n_in; (void)out_size; (void)ws_size;
    const float* raw  = (const float*)d_in[0];
    const float* eegf = (const float*)d_in[1];
    const float* eps  = (const float*)d_in[2];
    const float* fgw1 = (const float*)d_in[3];
    const float* fgb1 = (const float*)d_in[4];
    const float* fgw2 = (const float*)d_in[5];
    const float* fgb2 = (const float*)d_in[6];
    const float* ew1  = (const float*)d_in[7];
    const float* eb1  = (const float*)d_in[8];
    const float* bn1g = (const float*)d_in[9];
    const float* bn1b = (const float*)d_in[10];
    const float* ew2  = (const float*)d_in[11];
    const float* eb2  = (const float*)d_in[12];
    const float* bn2g = (const float*)d_in[13];
    const float* bn2b = (const float*)d_in[14];
    const float* muw  = (const float*)d_in[15];
    const float* mub  = (const float*)d_in[16];
    const float* lvw  = (const float*)d_in[17];
    const float* lvb  = (const float*)d_in[18];
    const float* dw1  = (const float*)d_in[19];
    const float* db1  = (const float*)d_in[20];
    const float* dw2  = (const float*)d_in[21];
    const float* db2  = (const float*)d_in[22];

    float* ws     = (float*)d_ws;
    float* stats1 = ws + WS_STATS1;
    float* stats2 = ws + WS_STATS2;
    float* w1t    = ws + WS_W1T;
    float* w2t    = ws + WS_W2T;
    float* filt   = ws + WS_FILT;
    unsigned short* c1 = (unsigned short*)(ws + WS_C1);
    unsigned short* c2 = (unsigned short*)(ws + WS_C2);
    float* out    = (float*)d_out;

    hipLaunchKernelGGL(k_init, dim3(1), dim3(256), 0, stream, ew1, ew2, w1t, w2t, stats1);
    hipLaunchKernelGGL(k_fg, dim3(256), dim3(256), 0, stream,
                       eegf, fgw1, fgb1, fgw2, fgb2, filt);
    hipLaunchKernelGGL(k_conv1, dim3(2048), dim3(320), 0, stream,
                       raw, eb1, filt, w1t, c1, stats1);
    hipLaunchKernelGGL(k_conv2, dim3(2048), dim3(256), 0, stream,
                       eb2, bn1g, bn1b, stats1, w2t, c1, c2, stats2);
    hipLaunchKernelGGL(k_head, dim3(1024), dim3(256), 0, stream,
                       eps, muw, mub, lvw, lvb, dw1, db1, dw2, db2,
                       c2, stats2, bn2g, bn2b, out);
}